// Round 1
// baseline (135.984 us; speedup 1.0000x reference)
//
#include <hip/hip_runtime.h>
#include <hip/hip_bf16.h>

typedef __attribute__((ext_vector_type(8))) short bf16x8;
typedef __attribute__((ext_vector_type(4))) float f32x4;
typedef __attribute__((ext_vector_type(4))) unsigned short u16x4;
typedef __attribute__((ext_vector_type(4))) float float4_t;

static constexpr int Bn = 4, Sn = 2048, Dn = 1024, Kn = 128;
static constexpr int ODn = Dn + Kn;   // 1152

__device__ __forceinline__ unsigned short f2bf(float f) {
    union { float f; unsigned int u; } v; v.f = f;
    unsigned int u = v.u;
    return (unsigned short)((u + 0x7fffu + ((u >> 16) & 1u)) >> 16);
}

// ---------------- kernel 1: weights -> bf16, transposed Wt[w][c][k] ----------------
__global__ __launch_bounds__(256) void wt_prep(const float* __restrict__ Wq,
                                               const float* __restrict__ Wk,
                                               const float* __restrict__ Wv,
                                               unsigned short* __restrict__ Wt) {
    __shared__ unsigned short tile[32][34];
    int k0 = blockIdx.x * 32, c0 = blockIdx.y * 32, w = blockIdx.z;
    const float* W = (w == 0) ? Wq : (w == 1) ? Wk : Wv;
    int tc = threadIdx.x & 31;
    int tr = (threadIdx.x >> 5) * 4;
#pragma unroll
    for (int i = 0; i < 4; ++i)
        tile[tr + i][tc] = f2bf(W[(size_t)(k0 + tr + i) * Kn + c0 + tc]);
    __syncthreads();
    unsigned short* dst = Wt + (size_t)w * Kn * Dn;
#pragma unroll
    for (int i = 0; i < 4; ++i)
        dst[(size_t)(c0 + tr + i) * Dn + k0 + tc] = tile[tc][tr + i];
}

// ---------------- kernel 2: fused QKV projection + input passthrough ----------------
// BM=64 rows/block, BK=32, 4 waves, wave w owns cols [w*96, w*96+96).
__global__ __launch_bounds__(256, 2) void proj_kernel(
    const float* __restrict__ X, const unsigned short* __restrict__ Wt,
    const float* __restrict__ bq, const float* __restrict__ bk, const float* __restrict__ bv,
    float* __restrict__ out,
    unsigned short* __restrict__ qws, unsigned short* __restrict__ kws,
    unsigned short* __restrict__ vtws) {
    __shared__ __align__(16) unsigned short Alds[64 * 32];    // swizzled
    __shared__ __align__(16) unsigned short Wlds[384 * 32];   // swizzled
    const int m0 = blockIdx.x * 64;
    const int t = threadIdx.x;
    const int lane = t & 63, wn = t >> 6;
    const int lr = lane & 15, lg = lane >> 4;
    f32x4 acc[4][6] = {};

    for (int k0 = 0; k0 < Dn; k0 += 32) {
        __syncthreads();
        // stage A (64x32 fp32 -> bf16) + passthrough to out
#pragma unroll
        for (int p = 0; p < 2; ++p) {
            int n = t + p * 256;
            int row = n >> 3, f4 = n & 7;
            float4_t v = *(const float4_t*)(X + (size_t)(m0 + row) * Dn + k0 + f4 * 4);
            *(float4_t*)(out + (size_t)(m0 + row) * ODn + k0 + f4 * 4) = v;
            u16x4 hv;
            hv[0] = f2bf(v[0]); hv[1] = f2bf(v[1]); hv[2] = f2bf(v[2]); hv[3] = f2bf(v[3]);
            int off = (row * 64 + f4 * 8) ^ ((row & 7) << 4);
            *(u16x4*)((char*)Alds + off) = hv;
        }
        // stage Wt tile: 384 cols x 32 k (bf16)
#pragma unroll
        for (int p = 0; p < 6; ++p) {
            int n = t + p * 256;
            int c = n >> 2, seg = n & 3;
            bf16x8 v = *(const bf16x8*)(Wt + (size_t)c * Dn + k0 + seg * 8);
            int off = (c * 64 + seg * 16) ^ ((c & 7) << 4);
            *(bf16x8*)((char*)Wlds + off) = v;
        }
        __syncthreads();
        bf16x8 af[4], bfr[6];
#pragma unroll
        for (int mi = 0; mi < 4; ++mi) {
            int row = mi * 16 + lr;
            int off = (row * 64 + lg * 16) ^ ((row & 7) << 4);
            af[mi] = *(const bf16x8*)((const char*)Alds + off);
        }
#pragma unroll
        for (int ni = 0; ni < 6; ++ni) {
            int col = wn * 96 + ni * 16 + lr;
            int off = (col * 64 + lg * 16) ^ ((col & 7) << 4);
            bfr[ni] = *(const bf16x8*)((const char*)Wlds + off);
        }
#pragma unroll
        for (int mi = 0; mi < 4; ++mi)
#pragma unroll
            for (int ni = 0; ni < 6; ++ni)
                acc[mi][ni] = __builtin_amdgcn_mfma_f32_16x16x32_bf16(af[mi], bfr[ni], acc[mi][ni], 0, 0, 0);
    }
    // epilogue: q,k row-major bf16; v stored transposed Vt[b][c][s]
#pragma unroll
    for (int ni = 0; ni < 6; ++ni) {
        int gcol = wn * 96 + ni * 16 + lr;
        int buf = gcol >> 7, ci = gcol & 127;
        float bias = (buf == 0 ? bq : buf == 1 ? bk : bv)[ci];
#pragma unroll
        for (int mi = 0; mi < 4; ++mi) {
#pragma unroll
            for (int r = 0; r < 4; ++r) {
                int grow = m0 + mi * 16 + lg * 4 + r;
                unsigned short hv = f2bf(acc[mi][ni][r] + bias);
                if (buf == 0) qws[(size_t)grow * Kn + ci] = hv;
                else if (buf == 1) kws[(size_t)grow * Kn + ci] = hv;
                else {
                    int bb = grow >> 11, ss = grow & 2047;
                    vtws[((size_t)bb * Kn + ci) * Sn + ss] = hv;
                }
            }
        }
    }
}

// ---------------- kernel 3: causal flash attention ----------------
// One block = 64 Q rows (4 waves x 16 rows), KV tiles of 64.
__global__ __launch_bounds__(256, 2) void attn_kernel(
    const unsigned short* __restrict__ qws, const unsigned short* __restrict__ kws,
    const unsigned short* __restrict__ vtws, float* __restrict__ out) {
    __shared__ __align__(16) unsigned short Klds[64 * 128];   // [kv][d] swizzled
    __shared__ __align__(16) unsigned short Vlds[128 * 64];   // [vcol][kv] swizzled
    __shared__ __align__(16) unsigned short Plds[4][16 * 64]; // per-wave [q][kv] swizzled
    constexpr float SCALE = 0.08838834764831845f;  // 1/sqrt(128)
    constexpr float L2E = 1.4426950408889634f;
    const int t = threadIdx.x, lane = t & 63, wid = t >> 6;
    const int lr = lane & 15, lg = lane >> 4;
    const int NQT = Sn / 64;                        // 32
    const int qt = NQT - 1 - (int)(blockIdx.x & (NQT - 1));  // longest tiles first
    const int b = blockIdx.x >> 5;
    const int qrow0 = qt * 64 + wid * 16;
    const unsigned short* qbase = qws + ((size_t)b * Sn + qrow0) * Kn;
    bf16x8 qf[4];
#pragma unroll
    for (int kk = 0; kk < 4; ++kk)
        qf[kk] = *(const bf16x8*)(qbase + (size_t)lr * Kn + kk * 32 + lg * 8);
    f32x4 o[8] = {};
    float mrow[4] = {-1e30f, -1e30f, -1e30f, -1e30f};
    float lrow[4] = {0.f, 0.f, 0.f, 0.f};
    const unsigned short* kb = kws + (size_t)b * Sn * Kn;
    const unsigned short* vtb = vtws + (size_t)b * Kn * Sn;
    const int ntiles = qt + 1;

    for (int it = 0; it < ntiles; ++it) {
        const int kv0 = it * 64;
        __syncthreads();
#pragma unroll
        for (int p = 0; p < 4; ++p) {   // K tile 64x128
            int n = t + p * 256;
            int row = n >> 4, seg = n & 15;
            bf16x8 v = *(const bf16x8*)(kb + (size_t)(kv0 + row) * Kn + seg * 8);
            int off = (row * 256 + seg * 16) ^ ((row & 7) << 4);
            *(bf16x8*)((char*)Klds + off) = v;
        }
#pragma unroll
        for (int p = 0; p < 4; ++p) {   // Vt tile 128x64
            int n = t + p * 256;
            int c = n >> 3, seg = n & 7;
            bf16x8 v = *(const bf16x8*)(vtb + (size_t)c * Sn + kv0 + seg * 8);
            int off = (c * 128 + seg * 16) ^ ((c & 7) << 4);
            *(bf16x8*)((char*)Vlds + off) = v;
        }
        __syncthreads();
        // QK^T
        f32x4 s[4] = {};
#pragma unroll
        for (int n = 0; n < 4; ++n) {
            int kvr = n * 16 + lr;
#pragma unroll
            for (int kk = 0; kk < 4; ++kk) {
                int off = (kvr * 256 + kk * 64 + lg * 16) ^ ((kvr & 7) << 4);
                bf16x8 kf = *(const bf16x8*)((const char*)Klds + off);
                s[n] = __builtin_amdgcn_mfma_f32_16x16x32_bf16(qf[kk], kf, s[n], 0, 0, 0);
            }
        }
        // scale + causal mask
#pragma unroll
        for (int n = 0; n < 4; ++n) {
            int kvg = kv0 + n * 16 + lr;
#pragma unroll
            for (int r = 0; r < 4; ++r) {
                float sv = s[n][r] * SCALE;
                int qg = qrow0 + lg * 4 + r;
                s[n][r] = (kvg > qg) ? -1e30f : sv;
            }
        }
        // online softmax: row lives across the 16 lanes sharing lg
        float tmax[4], rsum[4], alpha[4];
#pragma unroll
        for (int r = 0; r < 4; ++r)
            tmax[r] = fmaxf(fmaxf(s[0][r], s[1][r]), fmaxf(s[2][r], s[3][r]));
#pragma unroll
        for (int d = 1; d < 16; d <<= 1)
#pragma unroll
            for (int r = 0; r < 4; ++r)
                tmax[r] = fmaxf(tmax[r], __shfl_xor(tmax[r], d));
#pragma unroll
        for (int r = 0; r < 4; ++r) {
            float mnew = fmaxf(mrow[r], tmax[r]);
            alpha[r] = exp2f((mrow[r] - mnew) * L2E);
            mrow[r] = mnew;
            rsum[r] = 0.f;
        }
        unsigned short pb[4][4];
#pragma unroll
        for (int n = 0; n < 4; ++n)
#pragma unroll
            for (int r = 0; r < 4; ++r) {
                float p = exp2f((s[n][r] - mrow[r]) * L2E);
                rsum[r] += p;
                pb[n][r] = f2bf(p);
            }
#pragma unroll
        for (int d = 1; d < 16; d <<= 1)
#pragma unroll
            for (int r = 0; r < 4; ++r)
                rsum[r] += __shfl_xor(rsum[r], d);
#pragma unroll
        for (int r = 0; r < 4; ++r)
            lrow[r] = lrow[r] * alpha[r] + rsum[r];
#pragma unroll
        for (int v = 0; v < 8; ++v)
#pragma unroll
            for (int r = 0; r < 4; ++r)
                o[v][r] *= alpha[r];
        // P -> per-wave LDS (D-layout to A-layout)
        char* pbase = (char*)&Plds[wid][0];
#pragma unroll
        for (int n = 0; n < 4; ++n)
#pragma unroll
            for (int r = 0; r < 4; ++r) {
                int q = lg * 4 + r, kv = n * 16 + lr;
                int off = (q * 128 + kv * 2) ^ ((q & 7) << 4);
                *(unsigned short*)(pbase + off) = pb[n][r];
            }
        // PV
        bf16x8 pa[2];
#pragma unroll
        for (int kk = 0; kk < 2; ++kk) {
            int aoff = (lr * 128 + kk * 64 + lg * 16) ^ ((lr & 7) << 4);
            pa[kk] = *(const bf16x8*)((const char*)pbase + aoff);
        }
#pragma unroll
        for (int v = 0; v < 8; ++v) {
            int vcol = v * 16 + lr;
#pragma unroll
            for (int kk = 0; kk < 2; ++kk) {
                int boff = (vcol * 128 + kk * 64 + lg * 16) ^ ((vcol & 7) << 4);
                bf16x8 vb = *(const bf16x8*)((const char*)Vlds + boff);
                o[v] = __builtin_amdgcn_mfma_f32_16x16x32_bf16(pa[kk], vb, o[v], 0, 0, 0);
            }
        }
    }
    // epilogue: out[.., 1024 + vcol] = o / l
#pragma unroll
    for (int v = 0; v < 8; ++v) {
#pragma unroll
        for (int r = 0; r < 4; ++r) {
            int grow = b * Sn + qrow0 + lg * 4 + r;
            out[(size_t)grow * ODn + Dn + v * 16 + lr] = o[v][r] / lrow[r];
        }
    }
}

extern "C" void kernel_launch(void* const* d_in, const int* in_sizes, int n_in,
                              void* d_out, int out_size, void* d_ws, size_t ws_size,
                              hipStream_t stream) {
    const float* X  = (const float*)d_in[0];
    const float* Wq = (const float*)d_in[1];
    const float* bq = (const float*)d_in[2];
    const float* Wk = (const float*)d_in[3];
    const float* bk = (const float*)d_in[4];
    const float* Wv = (const float*)d_in[5];
    const float* bv = (const float*)d_in[6];
    float* out = (float*)d_out;

    unsigned short* Wt   = (unsigned short*)d_ws;                    // 3*128*1024
    unsigned short* qws  = Wt  + (size_t)3 * Kn * Dn;                // 8192*128
    unsigned short* kws  = qws + (size_t)Bn * Sn * Kn;
    unsigned short* vtws = kws + (size_t)Bn * Sn * Kn;               // [4][128][2048]

    wt_prep<<<dim3(32, 4, 3), 256, 0, stream>>>(Wq, Wk, Wv, Wt);
    proj_kernel<<<128, 256, 0, stream>>>(X, Wt, bq, bk, bv, out, qws, kws, vtws);
    attn_kernel<<<128, 256, 0, stream>>>(qws, kws, vtws, out);
}

// Round 2
// 78.724 us; speedup vs baseline: 1.7274x; 1.7274x over previous
//
#include <hip/hip_runtime.h>
#include <hip/hip_bf16.h>

typedef __attribute__((ext_vector_type(8))) short bf16x8;
typedef __attribute__((ext_vector_type(4))) float f32x4;
typedef __attribute__((ext_vector_type(4))) unsigned short u16x4;
typedef __attribute__((ext_vector_type(4))) float float4_t;

static constexpr int Bn = 4, Sn = 2048, Dn = 1024, Kn = 128;
static constexpr int ODn = Dn + Kn;   // 1152
static constexpr int CPB = 80;        // kv-chunks per batch (sum over 32 qtiles of ceil((qt+1)/8))
static constexpr float L2E = 1.4426950408889634f;

__device__ __forceinline__ unsigned short f2bf(float f) {
    union { float f; unsigned int u; } v; v.f = f;
    unsigned int u = v.u;
    return (unsigned short)((u + 0x7fffu + ((u >> 16) & 1u)) >> 16);
}

#define GLOAD16(g, l) __builtin_amdgcn_global_load_lds( \
    (const __attribute__((address_space(1))) void*)(g), \
    (__attribute__((address_space(3))) void*)(l), 16, 0, 0)

// ---------------- kernel 1: weights -> bf16, transposed Wt[w][c][k] ----------------
__global__ __launch_bounds__(256) void wt_prep(const float* __restrict__ Wq,
                                               const float* __restrict__ Wk,
                                               const float* __restrict__ Wv,
                                               unsigned short* __restrict__ Wt) {
    __shared__ unsigned short tile[32][34];
    int k0 = blockIdx.x * 32, c0 = blockIdx.y * 32, w = blockIdx.z;
    const float* W = (w == 0) ? Wq : (w == 1) ? Wk : Wv;
    int tc = threadIdx.x & 31;
    int tr = (threadIdx.x >> 5) * 4;
#pragma unroll
    for (int i = 0; i < 4; ++i)
        tile[tr + i][tc] = f2bf(W[(size_t)(k0 + tr + i) * Kn + c0 + tc]);
    __syncthreads();
    unsigned short* dst = Wt + (size_t)w * Kn * Dn;
#pragma unroll
    for (int i = 0; i < 4; ++i)
        dst[(size_t)(c0 + tr + i) * Dn + k0 + tc] = tile[tc][tr + i];
}

// ---------------- kernel 2: fused QKV projection + passthrough ----------------
// BM=32 rows/block (grid=256), BK=32, 4 waves; wave wn owns cols [wn*96, wn*96+96).
// W staged direct-to-LDS (global_load_lds), A prefetched via registers (fp32->bf16 + passthrough).
__global__ __launch_bounds__(256, 2) void proj_kernel(
    const float* __restrict__ X, const unsigned short* __restrict__ Wt,
    const float* __restrict__ bq, const float* __restrict__ bk, const float* __restrict__ bv,
    float* __restrict__ out,
    unsigned short* __restrict__ qws, unsigned short* __restrict__ kws,
    unsigned short* __restrict__ vtws) {
    __shared__ __align__(16) unsigned short Alds[2][32 * 32];    // linear [row][k], 2 KB each
    __shared__ __align__(16) unsigned short Wlds[2][384 * 32];   // linear [col][k], 24 KB each
    const int m0 = blockIdx.x * 32;
    const int t = threadIdx.x;
    const int lane = t & 63, wn = t >> 6;
    const int lr = lane & 15, lg = lane >> 4;
    const int arow = t >> 3, af4 = t & 7;     // A-staging role: row, float4-seg

    const unsigned short* wsrc[6];
#pragma unroll
    for (int p = 0; p < 6; ++p) {
        int col = wn * 96 + p * 16 + (lane >> 2);
        int seg = lane & 3;
        wsrc[p] = Wt + (size_t)col * Dn + seg * 8;
    }
    f32x4 acc[2][6] = {};

    // prologue: stage k0=0 into buf 0
    {
        float4_t av = *(const float4_t*)(X + (size_t)(m0 + arow) * Dn + af4 * 4);
#pragma unroll
        for (int p = 0; p < 6; ++p)
            GLOAD16(wsrc[p], (char*)&Wlds[0][0] + wn * 6144 + p * 1024);
        *(float4_t*)(out + (size_t)(m0 + arow) * ODn + af4 * 4) = av;
        u16x4 hv;
        hv[0] = f2bf(av[0]); hv[1] = f2bf(av[1]); hv[2] = f2bf(av[2]); hv[3] = f2bf(av[3]);
        *(u16x4*)((char*)&Alds[0][0] + arow * 64 + af4 * 8) = hv;
    }
    __syncthreads();

    for (int k0 = 0; k0 < Dn; k0 += 32) {
        const int cur = (k0 >> 5) & 1;
        const int kn = k0 + 32;
        float4_t avn = {};
        if (kn < Dn) {
            avn = *(const float4_t*)(X + (size_t)(m0 + arow) * Dn + kn + af4 * 4);
#pragma unroll
            for (int p = 0; p < 6; ++p)
                GLOAD16(wsrc[p] + kn, (char*)&Wlds[cur ^ 1][0] + wn * 6144 + p * 1024);
        }
        bf16x8 afr[2], bfr[6];
#pragma unroll
        for (int mi = 0; mi < 2; ++mi)
            afr[mi] = *(const bf16x8*)((const char*)&Alds[cur][0] + (mi * 16 + lr) * 64 + lg * 16);
#pragma unroll
        for (int ni = 0; ni < 6; ++ni)
            bfr[ni] = *(const bf16x8*)((const char*)&Wlds[cur][0] + (wn * 96 + ni * 16 + lr) * 64 + lg * 16);
        __builtin_amdgcn_s_setprio(1);
#pragma unroll
        for (int mi = 0; mi < 2; ++mi)
#pragma unroll
            for (int ni = 0; ni < 6; ++ni)
                acc[mi][ni] = __builtin_amdgcn_mfma_f32_16x16x32_bf16(afr[mi], bfr[ni], acc[mi][ni], 0, 0, 0);
        __builtin_amdgcn_s_setprio(0);
        if (kn < Dn) {
            *(float4_t*)(out + (size_t)(m0 + arow) * ODn + kn + af4 * 4) = avn;
            u16x4 hv;
            hv[0] = f2bf(avn[0]); hv[1] = f2bf(avn[1]); hv[2] = f2bf(avn[2]); hv[3] = f2bf(avn[3]);
            *(u16x4*)((char*)&Alds[cur ^ 1][0] + arow * 64 + af4 * 8) = hv;
        }
        __syncthreads();
    }
    // epilogue: q,k row-major bf16; v transposed Vt[b][c][s]
#pragma unroll
    for (int ni = 0; ni < 6; ++ni) {
        int gcol = wn * 96 + ni * 16 + lr;
        int buf = gcol >> 7, ci = gcol & 127;
        float bias = (buf == 0 ? bq : buf == 1 ? bk : bv)[ci];
#pragma unroll
        for (int mi = 0; mi < 2; ++mi) {
#pragma unroll
            for (int r = 0; r < 4; ++r) {
                int grow = m0 + mi * 16 + lg * 4 + r;
                unsigned short hv = f2bf(acc[mi][ni][r] + bias);
                if (buf == 0) qws[(size_t)grow * Kn + ci] = hv;
                else if (buf == 1) kws[(size_t)grow * Kn + ci] = hv;
                else {
                    int bb = grow >> 11, ss = grow & 2047;
                    vtws[((size_t)bb * Kn + ci) * Sn + ss] = hv;
                }
            }
        }
    }
}

// ---------------- kernel 3: causal flash attention, split-KV ----------------
// block = (b, qtile of 64 rows, kv-chunk of <=8 tiles). 4 waves x 16 q-rows.
// K/V staged direct-to-LDS double-buffered, swizzle applied on the GLOBAL source.
__global__ __launch_bounds__(256, 2) void attn_kernel(
    const unsigned short* __restrict__ qws, const unsigned short* __restrict__ kws,
    const unsigned short* __restrict__ vtws,
    float* __restrict__ part_o, float* __restrict__ part_ml) {
    __shared__ __align__(16) unsigned short Klds[2][64 * 128];   // [kv][d] swizzled
    __shared__ __align__(16) unsigned short Vlds[2][128 * 64];   // [vcol][kv] swizzled
    __shared__ __align__(16) unsigned short Plds[4][16 * 64];    // per-wave
    constexpr float SCALE = 0.08838834764831845f;  // 1/sqrt(128)
    const int t = threadIdx.x, lane = t & 63, wid = t >> 6;
    const int lr = lane & 15, lg = lane >> 4;
    const int pidx = blockIdx.x;
    const int b = pidx / CPB;
    const int idx = pidx - b * CPB;
    int qt, c;
    if (idx < 8)       { qt = idx;                c = 0; }
    else if (idx < 24) { int r = idx - 8;  qt = 8  + (r >> 1); c = r & 1; }
    else if (idx < 48) { int r = idx - 24; int q3 = r / 3; qt = 16 + q3; c = r - q3 * 3; }
    else               { int r = idx - 48; qt = 24 + (r >> 2); c = r & 3; }
    const int it0 = c * 8;
    const int it1 = (c * 8 + 8 < qt + 1) ? (c * 8 + 8) : (qt + 1);
    const int qrow0 = qt * 64 + wid * 16;

    const unsigned short* kb  = kws  + (size_t)b * Sn * Kn;
    const unsigned short* vtb = vtws + (size_t)b * Kn * Sn;
    // pre-swizzled per-lane global sources (LDS dest stays linear for global_load_lds)
    const unsigned short* ksrc[4];
    const unsigned short* vsrc[4];
#pragma unroll
    for (int p = 0; p < 4; ++p) {
        int row = wid * 16 + p * 4 + (lane >> 4);
        int seg = lane & 15;
        ksrc[p] = kb + (size_t)row * Kn + ((seg ^ (row & 7)) * 8);
        int cc = wid * 32 + p * 8 + (lane >> 3);
        int sg = lane & 7;
        vsrc[p] = vtb + (size_t)cc * Sn + ((sg ^ (cc & 7)) * 8);
    }
    auto stage = [&](int buf, int it) {
#pragma unroll
        for (int p = 0; p < 4; ++p) {
            GLOAD16(ksrc[p] + (size_t)it * (64 * Kn), (char*)&Klds[buf][0] + wid * 4096 + p * 1024);
            GLOAD16(vsrc[p] + (size_t)it * 64,        (char*)&Vlds[buf][0] + wid * 4096 + p * 1024);
        }
    };

    const unsigned short* qbase = qws + ((size_t)b * Sn + qrow0) * Kn;
    bf16x8 qf[4];
#pragma unroll
    for (int kk = 0; kk < 4; ++kk)
        qf[kk] = *(const bf16x8*)(qbase + (size_t)lr * Kn + kk * 32 + lg * 8);
    f32x4 o[8] = {};
    float mrow[4] = {-1e30f, -1e30f, -1e30f, -1e30f};
    float lrow[4] = {0.f, 0.f, 0.f, 0.f};

    stage(0, it0);
    __syncthreads();

    for (int it = it0; it < it1; ++it) {
        const int cur = (it - it0) & 1;
        if (it + 1 < it1) stage(cur ^ 1, it + 1);
        const int kv0 = it * 64;
        // QK^T
        f32x4 s[4] = {};
        __builtin_amdgcn_s_setprio(1);
#pragma unroll
        for (int n = 0; n < 4; ++n) {
            int kvr = n * 16 + lr;
#pragma unroll
            for (int kk = 0; kk < 4; ++kk) {
                int off = (kvr * 256 + kk * 64 + lg * 16) ^ ((kvr & 7) << 4);
                bf16x8 kf = *(const bf16x8*)((const char*)&Klds[cur][0] + off);
                s[n] = __builtin_amdgcn_mfma_f32_16x16x32_bf16(qf[kk], kf, s[n], 0, 0, 0);
            }
        }
        __builtin_amdgcn_s_setprio(0);
        // scale + causal mask
#pragma unroll
        for (int n = 0; n < 4; ++n) {
            int kvg = kv0 + n * 16 + lr;
#pragma unroll
            for (int r = 0; r < 4; ++r) {
                float sv = s[n][r] * SCALE;
                int qg = qrow0 + lg * 4 + r;
                s[n][r] = (kvg > qg) ? -1e30f : sv;
            }
        }
        // online softmax (row = 16 lanes sharing lg)
        float tmax[4], rsum[4], alpha[4];
#pragma unroll
        for (int r = 0; r < 4; ++r)
            tmax[r] = fmaxf(fmaxf(s[0][r], s[1][r]), fmaxf(s[2][r], s[3][r]));
#pragma unroll
        for (int d = 1; d < 16; d <<= 1)
#pragma unroll
            for (int r = 0; r < 4; ++r)
                tmax[r] = fmaxf(tmax[r], __shfl_xor(tmax[r], d));
#pragma unroll
        for (int r = 0; r < 4; ++r) {
            float mnew = fmaxf(mrow[r], tmax[r]);
            alpha[r] = exp2f((mrow[r] - mnew) * L2E);
            mrow[r] = mnew;
            rsum[r] = 0.f;
        }
        unsigned short pb[4][4];
#pragma unroll
        for (int n = 0; n < 4; ++n)
#pragma unroll
            for (int r = 0; r < 4; ++r) {
                float p = exp2f((s[n][r] - mrow[r]) * L2E);
                rsum[r] += p;
                pb[n][r] = f2bf(p);
            }
#pragma unroll
        for (int d = 1; d < 16; d <<= 1)
#pragma unroll
            for (int r = 0; r < 4; ++r)
                rsum[r] += __shfl_xor(rsum[r], d);
#pragma unroll
        for (int r = 0; r < 4; ++r)
            lrow[r] = lrow[r] * alpha[r] + rsum[r];
#pragma unroll
        for (int v = 0; v < 8; ++v)
#pragma unroll
            for (int r = 0; r < 4; ++r)
                o[v][r] *= alpha[r];
        // P -> per-wave LDS (D-layout to A-layout)
        char* pbase = (char*)&Plds[wid][0];
#pragma unroll
        for (int n = 0; n < 4; ++n)
#pragma unroll
            for (int r = 0; r < 4; ++r) {
                int q = lg * 4 + r, kv = n * 16 + lr;
                int off = (q * 128 + kv * 2) ^ ((q & 7) << 4);
                *(unsigned short*)(pbase + off) = pb[n][r];
            }
        // PV
        bf16x8 pa[2];
#pragma unroll
        for (int kk = 0; kk < 2; ++kk) {
            int aoff = (lr * 128 + kk * 64 + lg * 16) ^ ((lr & 7) << 4);
            pa[kk] = *(const bf16x8*)((const char*)pbase + aoff);
        }
        __builtin_amdgcn_s_setprio(1);
#pragma unroll
        for (int v = 0; v < 8; ++v) {
            int vcol = v * 16 + lr;
#pragma unroll
            for (int kk = 0; kk < 2; ++kk) {
                int boff = (vcol * 128 + kk * 64 + lg * 16) ^ ((vcol & 7) << 4);
                bf16x8 vb = *(const bf16x8*)((const char*)&Vlds[cur][0] + boff);
                o[v] = __builtin_amdgcn_mfma_f32_16x16x32_bf16(pa[kk], vb, o[v], 0, 0, 0);
            }
        }
        __builtin_amdgcn_s_setprio(0);
        __syncthreads();   // drains prefetch vmcnt(0) + separates buffers
    }
    // epilogue: write partial o (undivided), m, l
    const size_t pbo = (size_t)pidx * (64 * 128);
#pragma unroll
    for (int v = 0; v < 8; ++v)
#pragma unroll
        for (int r = 0; r < 4; ++r) {
            int row = wid * 16 + lg * 4 + r;
            part_o[pbo + (size_t)row * 128 + v * 16 + lr] = o[v][r];
        }
    if (lr == 0) {
#pragma unroll
        for (int r = 0; r < 4; ++r) {
            int row = wid * 16 + lg * 4 + r;
            part_ml[(size_t)pidx * 128 + row * 2]     = mrow[r];
            part_ml[(size_t)pidx * 128 + row * 2 + 1] = lrow[r];
        }
    }
}

// ---------------- kernel 4: combine partials ----------------
// grid = (b, qt, rowhalf) = 4*32*2 = 256 blocks x 256 threads.
__global__ __launch_bounds__(256) void reduce_kernel(
    const float* __restrict__ part_o, const float* __restrict__ part_ml,
    float* __restrict__ out) {
    const int bid = blockIdx.x;
    const int rh = bid & 1, bq = bid >> 1;
    const int qt = bq & 31, b = bq >> 5;
    const int g = qt >> 3, nch = g + 1;
    const int cum[4] = {0, 8, 24, 48};
    const int idx0 = cum[g] + (qt - (g << 3)) * nch;
    const int pidx0 = b * CPB + idx0;
    const int t = threadIdx.x;
    const int row = rh * 32 + (t >> 3);
    const int col0 = (t & 7) * 16;

    float mc[4], lc[4];
#pragma unroll
    for (int cc = 0; cc < 4; ++cc) { mc[cc] = -1e30f; lc[cc] = 0.f; }
#pragma unroll
    for (int cc = 0; cc < 4; ++cc)
        if (cc < nch) {
            mc[cc] = part_ml[(size_t)(pidx0 + cc) * 128 + row * 2];
            lc[cc] = part_ml[(size_t)(pidx0 + cc) * 128 + row * 2 + 1];
        }
    float m = fmaxf(fmaxf(mc[0], mc[1]), fmaxf(mc[2], mc[3]));
    float w[4], l = 0.f;
#pragma unroll
    for (int cc = 0; cc < 4; ++cc) {
        w[cc] = exp2f((mc[cc] - m) * L2E);
        l += w[cc] * lc[cc];
    }
    float4_t acc4[4] = {};
#pragma unroll
    for (int cc = 0; cc < 4; ++cc)
        if (cc < nch) {
            const float* po = part_o + (size_t)(pidx0 + cc) * (64 * 128) + (size_t)row * 128 + col0;
#pragma unroll
            for (int j = 0; j < 4; ++j) {
                float4_t v = *(const float4_t*)(po + j * 4);
                acc4[j] += v * w[cc];
            }
        }
    const float inv = 1.f / l;
    const size_t grow = (size_t)b * Sn + qt * 64 + row;
#pragma unroll
    for (int j = 0; j < 4; ++j)
        *(float4_t*)(out + grow * ODn + Dn + col0 + j * 4) = acc4[j] * inv;
}

extern "C" void kernel_launch(void* const* d_in, const int* in_sizes, int n_in,
                              void* d_out, int out_size, void* d_ws, size_t ws_size,
                              hipStream_t stream) {
    const float* X  = (const float*)d_in[0];
    const float* Wq = (const float*)d_in[1];
    const float* bq = (const float*)d_in[2];
    const float* Wk = (const float*)d_in[3];
    const float* bk = (const float*)d_in[4];
    const float* Wv = (const float*)d_in[5];
    const float* bv = (const float*)d_in[6];
    float* out = (float*)d_out;

    unsigned short* Wt   = (unsigned short*)d_ws;                    // 3*128*1024 bf16
    unsigned short* qws  = Wt  + (size_t)3 * Kn * Dn;                // [4][2048][128] bf16
    unsigned short* kws  = qws + (size_t)Bn * Sn * Kn;
    unsigned short* vtws = kws + (size_t)Bn * Sn * Kn;               // [4][128][2048] bf16
    float* part_o  = (float*)(vtws + (size_t)Bn * Sn * Kn);          // [320][64][128] f32
    float* part_ml = part_o + (size_t)Bn * CPB * 64 * 128;           // [320][64][2] f32

    wt_prep<<<dim3(32, 4, 3), 256, 0, stream>>>(Wq, Wk, Wv, Wt);
    proj_kernel<<<256, 256, 0, stream>>>(X, Wt, bq, bk, bv, out, qws, kws, vtws);
    attn_kernel<<<Bn * CPB, 256, 0, stream>>>(qws, kws, vtws, part_o, part_ml);
    reduce_kernel<<<256, 256, 0, stream>>>(part_o, part_ml, out);
}

// Round 3
// 68.520 us; speedup vs baseline: 1.9846x; 1.1489x over previous
//
#include <hip/hip_runtime.h>
#include <hip/hip_bf16.h>

typedef __attribute__((ext_vector_type(8))) short bf16x8;
typedef __attribute__((ext_vector_type(4))) float f32x4;
typedef __attribute__((ext_vector_type(8))) unsigned short u16x8;
typedef __attribute__((ext_vector_type(4))) float float4_t;

static constexpr int Bn = 4, Sn = 2048, Dn = 1024, Kn = 128;
static constexpr int ODn = Dn + Kn;   // 1152
static constexpr int CH = 4;          // kv tiles per chunk
static constexpr int CPB = 144;       // sum over qt of ceil((qt+1)/CH)
static constexpr float L2E = 1.4426950408889634f;

__device__ __forceinline__ unsigned short f2bf(float f) {
    union { float f; unsigned int u; } v; v.f = f;
    unsigned int u = v.u;
    return (unsigned short)((u + 0x7fffu + ((u >> 16) & 1u)) >> 16);
}
__device__ __forceinline__ float bf2f(unsigned short h) {
    union { float f; unsigned int u; } v; v.u = ((unsigned int)h) << 16;
    return v.f;
}

#define GLOAD16(g, l) __builtin_amdgcn_global_load_lds( \
    (const __attribute__((address_space(1))) void*)(g), \
    (__attribute__((address_space(3))) void*)(l), 16, 0, 0)

// ---------------- kernel 1: weights -> bf16, transposed Wt[w][c][k] ----------------
__global__ __launch_bounds__(256) void wt_prep(const float* __restrict__ Wq,
                                               const float* __restrict__ Wk,
                                               const float* __restrict__ Wv,
                                               unsigned short* __restrict__ Wt) {
    __shared__ unsigned short tile[32][34];
    int k0 = blockIdx.x * 32, c0 = blockIdx.y * 32, w = blockIdx.z;
    const float* W = (w == 0) ? Wq : (w == 1) ? Wk : Wv;
    int tc = threadIdx.x & 31;
    int tr = (threadIdx.x >> 5) * 4;
#pragma unroll
    for (int i = 0; i < 4; ++i)
        tile[tr + i][tc] = f2bf(W[(size_t)(k0 + tr + i) * Kn + c0 + tc]);
    __syncthreads();
    unsigned short* dst = Wt + (size_t)w * Kn * Dn;
#pragma unroll
    for (int i = 0; i < 4; ++i)
        dst[(size_t)(c0 + tr + i) * Dn + k0 + tc] = tile[tc][tr + i];
}

// ---------------- kernel 2: fused QKV projection + passthrough ----------------
// grid=512: 128 M-blocks (BM=64) x 4 N-splits (96 cols). 4 waves, wave wn owns
// rows [wn*16,+16) x 96 cols. BK=64, double-buffered, swizzled LDS.
__global__ __launch_bounds__(256, 2) void proj_kernel(
    const float* __restrict__ X, const unsigned short* __restrict__ Wt,
    const float* __restrict__ bq, const float* __restrict__ bk, const float* __restrict__ bv,
    float* __restrict__ out,
    unsigned short* __restrict__ qws, unsigned short* __restrict__ kws,
    unsigned short* __restrict__ vtws) {
    __shared__ __align__(16) unsigned short Alds[2][64 * 64];   // 8 KB each, [row][k] swizzled
    __shared__ __align__(16) unsigned short Wlds[2][96 * 64];   // 12 KB each, [col][k] swizzled
    const int orig = blockIdx.x;
    const int wg = (orig & 7) * 64 + (orig >> 3);   // XCD-contiguous (512 = 8*64)
    const int m0 = (wg >> 2) * 64;
    const int ns = wg & 3;
    const int c0 = ns * 96;
    const int t = threadIdx.x, lane = t & 63, wn = t >> 6;
    const int lr = lane & 15, lg = lane >> 4;
    const int ar0 = t >> 3, ach = t & 7;   // A-staging: rows ar0, ar0+32; 16B chunk ach

    const unsigned short* wsrcp[3]; int wdst[3];
#pragma unroll
    for (int p = 0; p < 3; ++p) {
        int s = t + p * 256, col = s >> 3, kseg = s & 7;
        wsrcp[p] = Wt + (size_t)(c0 + col) * Dn + ((kseg ^ (col & 7)) * 8);
        wdst[p] = col * 128 + kseg * 16;
    }
    const float* xbase = X + (size_t)(m0 + ar0) * Dn + ach * 8;
    float* obase = out + (size_t)(m0 + ar0) * ODn + ach * 8;
    f32x4 acc[6] = {};
    float4_t va[4];

    auto loadA = [&](int k0) {
        va[0] = *(const float4_t*)(xbase + k0);
        va[1] = *(const float4_t*)(xbase + k0 + 4);
        va[2] = *(const float4_t*)(xbase + (size_t)32 * Dn + k0);
        va[3] = *(const float4_t*)(xbase + (size_t)32 * Dn + k0 + 4);
    };
    auto stageW = [&](int buf, int k0) {
#pragma unroll
        for (int p = 0; p < 3; ++p)
            GLOAD16(wsrcp[p] + k0, (char*)&Wlds[buf][0] + wdst[p]);
    };
    auto writeA = [&](int buf, int k0) {
        if ((k0 >> 8) == ns) {   // this block's passthrough quarter
            *(float4_t*)(obase + k0) = va[0];
            *(float4_t*)(obase + k0 + 4) = va[1];
            *(float4_t*)(obase + (size_t)32 * ODn + k0) = va[2];
            *(float4_t*)(obase + (size_t)32 * ODn + k0 + 4) = va[3];
        }
        u16x8 h0, h1;
#pragma unroll
        for (int j = 0; j < 4; ++j) {
            h0[j] = f2bf(va[0][j]); h0[j + 4] = f2bf(va[1][j]);
            h1[j] = f2bf(va[2][j]); h1[j + 4] = f2bf(va[3][j]);
        }
        const int r1 = ar0 + 32;
        *(u16x8*)((char*)&Alds[buf][0] + ar0 * 128 + ((ach * 16) ^ ((ar0 & 7) << 4))) = h0;
        *(u16x8*)((char*)&Alds[buf][0] + r1 * 128 + ((ach * 16) ^ ((r1 & 7) << 4))) = h1;
    };

    loadA(0); stageW(0, 0); writeA(0, 0);
    __syncthreads();

    const int arow = wn * 16 + lr;
    const int asw = (arow & 7) << 4;
    for (int k0 = 0; k0 < Dn; k0 += 64) {
        const int cur = (k0 >> 6) & 1;
        const int kn = k0 + 64;
        if (kn < Dn) { loadA(kn); stageW(cur ^ 1, kn); }   // issue-early
        __builtin_amdgcn_s_setprio(1);
#pragma unroll
        for (int kk = 0; kk < 2; ++kk) {
            bf16x8 afr = *(const bf16x8*)((const char*)&Alds[cur][0] +
                          arow * 128 + ((kk * 64 + lg * 16) ^ asw));
#pragma unroll
            for (int ni = 0; ni < 6; ++ni) {
                int col = ni * 16 + lr;
                bf16x8 bfr = *(const bf16x8*)((const char*)&Wlds[cur][0] +
                              col * 128 + ((kk * 64 + lg * 16) ^ ((col & 7) << 4)));
                acc[ni] = __builtin_amdgcn_mfma_f32_16x16x32_bf16(afr, bfr, acc[ni], 0, 0, 0);
            }
        }
        __builtin_amdgcn_s_setprio(0);
        if (kn < Dn) writeA(cur ^ 1, kn);                  // write-late
        __syncthreads();
    }
    // epilogue: q,k row-major bf16; v transposed Vt[b][c][s]
#pragma unroll
    for (int ni = 0; ni < 6; ++ni) {
        int gcol = c0 + ni * 16 + lr;
        int buf = gcol >> 7, ci = gcol & 127;
        float bias = (buf == 0 ? bq : buf == 1 ? bk : bv)[ci];
#pragma unroll
        for (int r = 0; r < 4; ++r) {
            int grow = m0 + wn * 16 + lg * 4 + r;
            unsigned short hv = f2bf(acc[ni][r] + bias);
            if (buf == 0) qws[(size_t)grow * Kn + ci] = hv;
            else if (buf == 1) kws[(size_t)grow * Kn + ci] = hv;
            else {
                int bb = grow >> 11, ss = grow & 2047;
                vtws[((size_t)bb * Kn + ci) * Sn + ss] = hv;
            }
        }
    }
}

// ---------------- kernel 3: causal flash attention, split-KV (CH=4) ----------------
__global__ __launch_bounds__(256, 2) void attn_kernel(
    const unsigned short* __restrict__ qws, const unsigned short* __restrict__ kws,
    const unsigned short* __restrict__ vtws,
    unsigned short* __restrict__ part_o, float* __restrict__ part_ml) {
    __shared__ __align__(16) unsigned short Klds[2][64 * 128];
    __shared__ __align__(16) unsigned short Vlds[2][128 * 64];
    __shared__ __align__(16) unsigned short Plds[4][16 * 64];
    constexpr float SCALE = 0.08838834764831845f;
    const int t = threadIdx.x, lane = t & 63, wid = t >> 6;
    const int lr = lane & 15, lg = lane >> 4;
    const int pidx = blockIdx.x;
    const int b = pidx / CPB;
    const int idx = pidx - b * CPB;
    int qt = 0, rem = idx;
    while (true) { int n = (qt + CH) >> 2; if (rem < n) break; rem -= n; ++qt; }
    const int c = rem;
    const int it0 = c * CH;
    const int it1 = (it0 + CH < qt + 1) ? (it0 + CH) : (qt + 1);
    const int qrow0 = qt * 64 + wid * 16;

    const unsigned short* kb  = kws  + (size_t)b * Sn * Kn;
    const unsigned short* vtb = vtws + (size_t)b * Kn * Sn;
    const unsigned short* ksrc[4];
    const unsigned short* vsrc[4];
#pragma unroll
    for (int p = 0; p < 4; ++p) {
        int row = wid * 16 + p * 4 + (lane >> 4);
        int seg = lane & 15;
        ksrc[p] = kb + (size_t)row * Kn + ((seg ^ (row & 7)) * 8);
        int cc = wid * 32 + p * 8 + (lane >> 3);
        int sg = lane & 7;
        vsrc[p] = vtb + (size_t)cc * Sn + ((sg ^ (cc & 7)) * 8);
    }
    auto stage = [&](int buf, int it) {
#pragma unroll
        for (int p = 0; p < 4; ++p) {
            GLOAD16(ksrc[p] + (size_t)it * (64 * Kn), (char*)&Klds[buf][0] + wid * 4096 + p * 1024);
            GLOAD16(vsrc[p] + (size_t)it * 64,        (char*)&Vlds[buf][0] + wid * 4096 + p * 1024);
        }
    };

    const unsigned short* qbase = qws + ((size_t)b * Sn + qrow0) * Kn;
    bf16x8 qf[4];
#pragma unroll
    for (int kk = 0; kk < 4; ++kk)
        qf[kk] = *(const bf16x8*)(qbase + (size_t)lr * Kn + kk * 32 + lg * 8);
    f32x4 o[8] = {};
    float mrow[4] = {-1e30f, -1e30f, -1e30f, -1e30f};
    float lrow[4] = {0.f, 0.f, 0.f, 0.f};

    stage(0, it0);
    __syncthreads();

    for (int it = it0; it < it1; ++it) {
        const int cur = (it - it0) & 1;
        if (it + 1 < it1) stage(cur ^ 1, it + 1);
        const int kv0 = it * 64;
        f32x4 s[4] = {};
        __builtin_amdgcn_s_setprio(1);
#pragma unroll
        for (int n = 0; n < 4; ++n) {
            int kvr = n * 16 + lr;
#pragma unroll
            for (int kk = 0; kk < 4; ++kk) {
                int off = (kvr * 256 + kk * 64 + lg * 16) ^ ((kvr & 7) << 4);
                bf16x8 kf = *(const bf16x8*)((const char*)&Klds[cur][0] + off);
                s[n] = __builtin_amdgcn_mfma_f32_16x16x32_bf16(qf[kk], kf, s[n], 0, 0, 0);
            }
        }
        __builtin_amdgcn_s_setprio(0);
        if (it == qt) {   // only the diagonal tile needs masking
#pragma unroll
            for (int n = 0; n < 4; ++n) {
                int kvg = kv0 + n * 16 + lr;
#pragma unroll
                for (int r = 0; r < 4; ++r) {
                    float sv = s[n][r] * SCALE;
                    int qg = qrow0 + lg * 4 + r;
                    s[n][r] = (kvg > qg) ? -1e30f : sv;
                }
            }
        } else {
#pragma unroll
            for (int n = 0; n < 4; ++n)
#pragma unroll
                for (int r = 0; r < 4; ++r)
                    s[n][r] *= SCALE;
        }
        float tmax[4], rsum[4], alpha[4];
#pragma unroll
        for (int r = 0; r < 4; ++r)
            tmax[r] = fmaxf(fmaxf(s[0][r], s[1][r]), fmaxf(s[2][r], s[3][r]));
#pragma unroll
        for (int d = 1; d < 16; d <<= 1)
#pragma unroll
            for (int r = 0; r < 4; ++r)
                tmax[r] = fmaxf(tmax[r], __shfl_xor(tmax[r], d));
#pragma unroll
        for (int r = 0; r < 4; ++r) {
            float mnew = fmaxf(mrow[r], tmax[r]);
            alpha[r] = exp2f((mrow[r] - mnew) * L2E);
            mrow[r] = mnew;
            rsum[r] = 0.f;
        }
        unsigned short pb[4][4];
#pragma unroll
        for (int n = 0; n < 4; ++n)
#pragma unroll
            for (int r = 0; r < 4; ++r) {
                float p = exp2f((s[n][r] - mrow[r]) * L2E);
                rsum[r] += p;
                pb[n][r] = f2bf(p);
            }
#pragma unroll
        for (int d = 1; d < 16; d <<= 1)
#pragma unroll
            for (int r = 0; r < 4; ++r)
                rsum[r] += __shfl_xor(rsum[r], d);
#pragma unroll
        for (int r = 0; r < 4; ++r)
            lrow[r] = lrow[r] * alpha[r] + rsum[r];
#pragma unroll
        for (int v = 0; v < 8; ++v)
#pragma unroll
            for (int r = 0; r < 4; ++r)
                o[v][r] *= alpha[r];
        char* pbase = (char*)&Plds[wid][0];
#pragma unroll
        for (int n = 0; n < 4; ++n)
#pragma unroll
            for (int r = 0; r < 4; ++r) {
                int q = lg * 4 + r, kv = n * 16 + lr;
                int off = (q * 128 + kv * 2) ^ ((q & 7) << 4);
                *(unsigned short*)(pbase + off) = pb[n][r];
            }
        bf16x8 pa[2];
#pragma unroll
        for (int kk = 0; kk < 2; ++kk) {
            int aoff = (lr * 128 + kk * 64 + lg * 16) ^ ((lr & 7) << 4);
            pa[kk] = *(const bf16x8*)((const char*)pbase + aoff);
        }
        __builtin_amdgcn_s_setprio(1);
#pragma unroll
        for (int v = 0; v < 8; ++v) {
            int vcol = v * 16 + lr;
#pragma unroll
            for (int kk = 0; kk < 2; ++kk) {
                int boff = (vcol * 128 + kk * 64 + lg * 16) ^ ((vcol & 7) << 4);
                bf16x8 vb = *(const bf16x8*)((const char*)&Vlds[cur][0] + boff);
                o[v] = __builtin_amdgcn_mfma_f32_16x16x32_bf16(pa[kk], vb, o[v], 0, 0, 0);
            }
        }
        __builtin_amdgcn_s_setprio(0);
        __syncthreads();
    }
    const size_t pbo = (size_t)pidx * (64 * 128);
#pragma unroll
    for (int v = 0; v < 8; ++v)
#pragma unroll
        for (int r = 0; r < 4; ++r) {
            int row = wid * 16 + lg * 4 + r;
            part_o[pbo + (size_t)row * 128 + v * 16 + lr] = f2bf(o[v][r]);
        }
    if (lr == 0) {
#pragma unroll
        for (int r = 0; r < 4; ++r) {
            int row = wid * 16 + lg * 4 + r;
            part_ml[(size_t)pidx * 128 + row * 2]     = mrow[r];
            part_ml[(size_t)pidx * 128 + row * 2 + 1] = lrow[r];
        }
    }
}

// ---------------- kernel 4: combine partials (up to 8 chunks) ----------------
__global__ __launch_bounds__(256) void reduce_kernel(
    const unsigned short* __restrict__ part_o, const float* __restrict__ part_ml,
    float* __restrict__ out) {
    const int bid = blockIdx.x;
    const int rh = bid & 1, bq = bid >> 1;
    const int qt = bq & 31, b = bq >> 5;
    const int nch = (qt + CH) >> 2;
    int idx0 = 0;
    for (int q = 0; q < qt; ++q) idx0 += (q + CH) >> 2;
    const int pidx0 = b * CPB + idx0;
    const int t = threadIdx.x;
    const int row = rh * 32 + (t >> 3);
    const int col0 = (t & 7) * 16;

    float mc[8], lc[8];
#pragma unroll
    for (int cc = 0; cc < 8; ++cc) { mc[cc] = -1e30f; lc[cc] = 0.f; }
#pragma unroll
    for (int cc = 0; cc < 8; ++cc)
        if (cc < nch) {
            mc[cc] = part_ml[(size_t)(pidx0 + cc) * 128 + row * 2];
            lc[cc] = part_ml[(size_t)(pidx0 + cc) * 128 + row * 2 + 1];
        }
    float m = -1e30f;
#pragma unroll
    for (int cc = 0; cc < 8; ++cc) m = fmaxf(m, mc[cc]);
    float l = 0.f;
    float accv[16] = {};
#pragma unroll
    for (int cc = 0; cc < 8; ++cc)
        if (cc < nch) {
            float w = exp2f((mc[cc] - m) * L2E);
            l += w * lc[cc];
            const unsigned short* po = part_o + (size_t)(pidx0 + cc) * (64 * 128) + (size_t)row * 128 + col0;
            bf16x8 v0 = *(const bf16x8*)(po);
            bf16x8 v1 = *(const bf16x8*)(po + 8);
#pragma unroll
            for (int j = 0; j < 8; ++j) {
                accv[j]     += w * bf2f((unsigned short)v0[j]);
                accv[8 + j] += w * bf2f((unsigned short)v1[j]);
            }
        }
    const float inv = 1.f / l;
    float* op = out + ((size_t)b * Sn + qt * 64 + row) * ODn + Dn + col0;
#pragma unroll
    for (int j = 0; j < 4; ++j) {
        float4_t v = { accv[j*4] * inv, accv[j*4+1] * inv, accv[j*4+2] * inv, accv[j*4+3] * inv };
        *(float4_t*)(op + j * 4) = v;
    }
}

extern "C" void kernel_launch(void* const* d_in, const int* in_sizes, int n_in,
                              void* d_out, int out_size, void* d_ws, size_t ws_size,
                              hipStream_t stream) {
    const float* X  = (const float*)d_in[0];
    const float* Wq = (const float*)d_in[1];
    const float* bq = (const float*)d_in[2];
    const float* Wk = (const float*)d_in[3];
    const float* bk = (const float*)d_in[4];
    const float* Wv = (const float*)d_in[5];
    const float* bv = (const float*)d_in[6];
    float* out = (float*)d_out;

    unsigned short* Wt   = (unsigned short*)d_ws;                    // 3*128*1024 bf16
    unsigned short* qws  = Wt  + (size_t)3 * Kn * Dn;                // [4][2048][128] bf16
    unsigned short* kws  = qws + (size_t)Bn * Sn * Kn;
    unsigned short* vtws = kws + (size_t)Bn * Sn * Kn;               // [4][128][2048] bf16
    unsigned short* part_o = vtws + (size_t)Bn * Sn * Kn;            // [576][64][128] bf16
    float* part_ml = (float*)(part_o + (size_t)Bn * CPB * 64 * 128); // [576][64][2] f32

    wt_prep<<<dim3(32, 4, 3), 256, 0, stream>>>(Wq, Wk, Wv, Wt);
    proj_kernel<<<512, 256, 0, stream>>>(X, Wt, bq, bk, bv, out, qws, kws, vtws);
    attn_kernel<<<Bn * CPB, 256, 0, stream>>>(qws, kws, vtws, part_o, part_ml);
    reduce_kernel<<<256, 256, 0, stream>>>(part_o, part_ml, out);
}

// Round 4
// 66.847 us; speedup vs baseline: 2.0343x; 1.0250x over previous
//
#include <hip/hip_runtime.h>
#include <hip/hip_bf16.h>

typedef __attribute__((ext_vector_type(8))) short bf16x8;
typedef __attribute__((ext_vector_type(4))) float f32x4;
typedef __attribute__((ext_vector_type(8))) unsigned short u16x8;
typedef __attribute__((ext_vector_type(4))) float float4_t;

static constexpr int Bn = 4, Sn = 2048, Dn = 1024, Kn = 128;
static constexpr int ODn = Dn + Kn;   // 1152
static constexpr int CH = 4;          // kv tiles per chunk
static constexpr int CPB = 144;       // sum over qt of ceil((qt+1)/CH)
static constexpr float L2E = 1.4426950408889634f;

__device__ __forceinline__ unsigned short f2bf(float f) {
    union { float f; unsigned int u; } v; v.f = f;
    unsigned int u = v.u;
    return (unsigned short)((u + 0x7fffu + ((u >> 16) & 1u)) >> 16);
}
__device__ __forceinline__ float bf2f(unsigned short h) {
    union { float f; unsigned int u; } v; v.u = ((unsigned int)h) << 16;
    return v.f;
}

#define GLOAD16(g, l) __builtin_amdgcn_global_load_lds( \
    (const __attribute__((address_space(1))) void*)(g), \
    (__attribute__((address_space(3))) void*)(l), 16, 0, 0)

// ---------------- kernel 1: weights -> bf16, transposed Wt[w][c][k] ----------------
__global__ __launch_bounds__(256) void wt_prep(const float* __restrict__ Wq,
                                               const float* __restrict__ Wk,
                                               const float* __restrict__ Wv,
                                               unsigned short* __restrict__ Wt) {
    __shared__ unsigned short tile[32][34];
    int k0 = blockIdx.x * 32, c0 = blockIdx.y * 32, w = blockIdx.z;
    const float* W = (w == 0) ? Wq : (w == 1) ? Wk : Wv;
    int tc = threadIdx.x & 31;
    int tr = (threadIdx.x >> 5) * 4;
#pragma unroll
    for (int i = 0; i < 4; ++i)
        tile[tr + i][tc] = f2bf(W[(size_t)(k0 + tr + i) * Kn + c0 + tc]);
    __syncthreads();
    unsigned short* dst = Wt + (size_t)w * Kn * Dn;
#pragma unroll
    for (int i = 0; i < 4; ++i)
        dst[(size_t)(c0 + tr + i) * Dn + k0 + tc] = tile[tc][tr + i];
}

// ---------------- kernel 2: fused QKV projection + passthrough ----------------
// grid=512: 128 M-blocks (BM=64) x 4 N-splits (96 cols). 4 waves in 2x2 grid,
// wave = 32 rows x 48 cols. BK=64, W tri-buffered LDS (counted vmcnt pipeline),
// A double-buffered reg->LDS. Raw s_barrier + s_waitcnt vmcnt(7) (never 0 in loop).
__global__ __launch_bounds__(256, 2) void proj_kernel(
    const float* __restrict__ X, const unsigned short* __restrict__ Wt,
    const float* __restrict__ bq, const float* __restrict__ bk, const float* __restrict__ bv,
    float* __restrict__ out,
    unsigned short* __restrict__ qws, unsigned short* __restrict__ kws,
    unsigned short* __restrict__ vtws) {
    __shared__ __align__(16) unsigned short Alds[2][64 * 64];   // 8 KB each
    __shared__ __align__(16) unsigned short Wlds[3][96 * 64];   // 12 KB each (tri-buffer)
    constexpr int NT = 16;                                      // K-tiles of 64
    const int orig = blockIdx.x;
    const int wg = (orig & 7) * 64 + (orig >> 3);   // XCD-contiguous (512 = 8*64)
    const int m0 = (wg >> 2) * 64;
    const int ns = wg & 3;
    const int c0 = ns * 96;
    const int t = threadIdx.x, lane = t & 63, wn = t >> 6;
    const int lr = lane & 15, lg = lane >> 4;
    const int wr = wn >> 1, wc = wn & 1;
    const int ar0 = t >> 3, ach = t & 7;   // A-staging: rows ar0, ar0+32; 16B chunk ach

    const unsigned short* wsrcp[3]; int wdst[3];
#pragma unroll
    for (int p = 0; p < 3; ++p) {
        int s = t + p * 256, col = s >> 3, kseg = s & 7;
        wsrcp[p] = Wt + (size_t)(c0 + col) * Dn + ((kseg ^ (col & 7)) * 8);
        wdst[p] = col * 128 + kseg * 16;
    }
    const float* xbase = X + (size_t)(m0 + ar0) * Dn + ach * 8;
    float* obase = out + (size_t)(m0 + ar0) * ODn + ach * 8;
    f32x4 acc[2][3] = {};
    float4_t va0[4], va1[4];

    auto loadA = [&](float4_t* va, int j) {
        const int k0 = j * 64;
        va[0] = *(const float4_t*)(xbase + k0);
        va[1] = *(const float4_t*)(xbase + k0 + 4);
        va[2] = *(const float4_t*)(xbase + (size_t)32 * Dn + k0);
        va[3] = *(const float4_t*)(xbase + (size_t)32 * Dn + k0 + 4);
    };
    auto stageW = [&](int wbuf, int j) {
#pragma unroll
        for (int p = 0; p < 3; ++p)
            GLOAD16(wsrcp[p] + j * 64, (char*)&Wlds[wbuf][0] + wdst[p]);
    };
    auto writeA = [&](const float4_t* va, int abuf, int j) {
        const int k0 = j * 64;
        if ((j >> 2) == ns) {   // this block's passthrough quarter
            *(float4_t*)(obase + k0) = va[0];
            *(float4_t*)(obase + k0 + 4) = va[1];
            *(float4_t*)(obase + (size_t)32 * ODn + k0) = va[2];
            *(float4_t*)(obase + (size_t)32 * ODn + k0 + 4) = va[3];
        }
        u16x8 h0, h1;
#pragma unroll
        for (int jj = 0; jj < 4; ++jj) {
            h0[jj] = f2bf(va[0][jj]); h0[jj + 4] = f2bf(va[1][jj]);
            h1[jj] = f2bf(va[2][jj]); h1[jj + 4] = f2bf(va[3][jj]);
        }
        const int r1 = ar0 + 32;
        *(u16x8*)((char*)&Alds[abuf][0] + ar0 * 128 + ((ach * 16) ^ ((ar0 & 7) << 4))) = h0;
        *(u16x8*)((char*)&Alds[abuf][0] + r1 * 128 + ((ach * 16) ^ ((r1 & 7) << 4))) = h1;
    };
    auto compute = [&](int abuf, int wbuf) {
        __builtin_amdgcn_s_setprio(1);
#pragma unroll
        for (int kk = 0; kk < 2; ++kk) {
            bf16x8 afr[2], bfr[3];
#pragma unroll
            for (int mi = 0; mi < 2; ++mi) {
                int row = wr * 32 + mi * 16 + lr;
                afr[mi] = *(const bf16x8*)((const char*)&Alds[abuf][0] +
                           row * 128 + ((kk * 64 + lg * 16) ^ ((row & 7) << 4)));
            }
#pragma unroll
            for (int ni = 0; ni < 3; ++ni) {
                int col = wc * 48 + ni * 16 + lr;
                bfr[ni] = *(const bf16x8*)((const char*)&Wlds[wbuf][0] +
                           col * 128 + ((kk * 64 + lg * 16) ^ ((col & 7) << 4)));
            }
#pragma unroll
            for (int mi = 0; mi < 2; ++mi)
#pragma unroll
                for (int ni = 0; ni < 3; ++ni)
                    acc[mi][ni] = __builtin_amdgcn_mfma_f32_16x16x32_bf16(afr[mi], bfr[ni], acc[mi][ni], 0, 0, 0);
        }
        __builtin_amdgcn_s_setprio(0);
    };

    // prologue: tiles 0,1 in flight
    loadA(va0, 0);  stageW(0, 0);
    loadA(va1, 1);  stageW(1, 1);
    writeA(va0, 0, 0);                       // compiler auto-waits for va0
    asm volatile("s_waitcnt vmcnt(7) lgkmcnt(0)" ::: "memory");
    __builtin_amdgcn_sched_barrier(0);
    __builtin_amdgcn_s_barrier();
    __builtin_amdgcn_sched_barrier(0);

    for (int ii = 0; ii < 14; ii += 2) {
        // i = ii (even): load va0 <- X(i+2), consume Alds[0], write va1=X(i+1) -> Alds[1]
        loadA(va0, ii + 2);  stageW((ii + 2) % 3, ii + 2);
        compute(0, ii % 3);
        writeA(va1, 1, ii + 1);
        asm volatile("s_waitcnt vmcnt(7) lgkmcnt(0)" ::: "memory");
        __builtin_amdgcn_sched_barrier(0);
        __builtin_amdgcn_s_barrier();
        __builtin_amdgcn_sched_barrier(0);
        // i = ii+1 (odd)
        loadA(va1, ii + 3);  stageW((ii + 3) % 3, ii + 3);
        compute(1, (ii + 1) % 3);
        writeA(va0, 0, ii + 2);
        asm volatile("s_waitcnt vmcnt(7) lgkmcnt(0)" ::: "memory");
        __builtin_amdgcn_sched_barrier(0);
        __builtin_amdgcn_s_barrier();
        __builtin_amdgcn_sched_barrier(0);
    }
    // i = 14: no new issue; write X(15); drain remaining
    compute(0, 14 % 3);
    writeA(va1, 1, 15);
    asm volatile("s_waitcnt vmcnt(0) lgkmcnt(0)" ::: "memory");
    __builtin_amdgcn_sched_barrier(0);
    __builtin_amdgcn_s_barrier();
    __builtin_amdgcn_sched_barrier(0);
    // i = 15
    compute(1, 15 % 3);

    // epilogue: q,k row-major bf16; v transposed Vt[b][c][s]
#pragma unroll
    for (int ni = 0; ni < 3; ++ni) {
        int gcol = c0 + wc * 48 + ni * 16 + lr;
        int buf = gcol >> 7, ci = gcol & 127;
        float bias = (buf == 0 ? bq : buf == 1 ? bk : bv)[ci];
#pragma unroll
        for (int mi = 0; mi < 2; ++mi) {
#pragma unroll
            for (int r = 0; r < 4; ++r) {
                int grow = m0 + wr * 32 + mi * 16 + lg * 4 + r;
                unsigned short hv = f2bf(acc[mi][ni][r] + bias);
                if (buf == 0) qws[(size_t)grow * Kn + ci] = hv;
                else if (buf == 1) kws[(size_t)grow * Kn + ci] = hv;
                else {
                    int bb = grow >> 11, ss = grow & 2047;
                    vtws[((size_t)bb * Kn + ci) * Sn + ss] = hv;
                }
            }
        }
    }
}

// ---------------- kernel 3: causal flash attention, split-KV (CH=4) ----------------
__global__ __launch_bounds__(256, 2) void attn_kernel(
    const unsigned short* __restrict__ qws, const unsigned short* __restrict__ kws,
    const unsigned short* __restrict__ vtws,
    unsigned short* __restrict__ part_o, float* __restrict__ part_ml) {
    __shared__ __align__(16) unsigned short Klds[2][64 * 128];
    __shared__ __align__(16) unsigned short Vlds[2][128 * 64];
    __shared__ __align__(16) unsigned short Plds[4][16 * 64];
    constexpr float SCALE = 0.08838834764831845f;
    const int t = threadIdx.x, lane = t & 63, wid = t >> 6;
    const int lr = lane & 15, lg = lane >> 4;
    const int pidx = blockIdx.x;
    const int b = pidx / CPB;
    const int idx = pidx - b * CPB;
    int qt = 0, rem = idx;
    while (true) { int n = (qt + CH) >> 2; if (rem < n) break; rem -= n; ++qt; }
    const int c = rem;
    const int it0 = c * CH;
    const int it1 = (it0 + CH < qt + 1) ? (it0 + CH) : (qt + 1);
    const int qrow0 = qt * 64 + wid * 16;

    const unsigned short* kb  = kws  + (size_t)b * Sn * Kn;
    const unsigned short* vtb = vtws + (size_t)b * Kn * Sn;
    const unsigned short* ksrc[4];
    const unsigned short* vsrc[4];
#pragma unroll
    for (int p = 0; p < 4; ++p) {
        int row = wid * 16 + p * 4 + (lane >> 4);
        int seg = lane & 15;
        ksrc[p] = kb + (size_t)row * Kn + ((seg ^ (row & 7)) * 8);
        int cc = wid * 32 + p * 8 + (lane >> 3);
        int sg = lane & 7;
        vsrc[p] = vtb + (size_t)cc * Sn + ((sg ^ (cc & 7)) * 8);
    }
    auto stage = [&](int buf, int it) {
#pragma unroll
        for (int p = 0; p < 4; ++p) {
            GLOAD16(ksrc[p] + (size_t)it * (64 * Kn), (char*)&Klds[buf][0] + wid * 4096 + p * 1024);
            GLOAD16(vsrc[p] + (size_t)it * 64,        (char*)&Vlds[buf][0] + wid * 4096 + p * 1024);
        }
    };

    const unsigned short* qbase = qws + ((size_t)b * Sn + qrow0) * Kn;
    bf16x8 qf[4];
#pragma unroll
    for (int kk = 0; kk < 4; ++kk)
        qf[kk] = *(const bf16x8*)(qbase + (size_t)lr * Kn + kk * 32 + lg * 8);
    f32x4 o[8] = {};
    float mrow[4] = {-1e30f, -1e30f, -1e30f, -1e30f};
    float lrow[4] = {0.f, 0.f, 0.f, 0.f};

    stage(0, it0);
    __syncthreads();

    for (int it = it0; it < it1; ++it) {
        const int cur = (it - it0) & 1;
        if (it + 1 < it1) stage(cur ^ 1, it + 1);
        const int kv0 = it * 64;
        f32x4 s[4] = {};
        __builtin_amdgcn_s_setprio(1);
#pragma unroll
        for (int n = 0; n < 4; ++n) {
            int kvr = n * 16 + lr;
#pragma unroll
            for (int kk = 0; kk < 4; ++kk) {
                int off = (kvr * 256 + kk * 64 + lg * 16) ^ ((kvr & 7) << 4);
                bf16x8 kf = *(const bf16x8*)((const char*)&Klds[cur][0] + off);
                s[n] = __builtin_amdgcn_mfma_f32_16x16x32_bf16(qf[kk], kf, s[n], 0, 0, 0);
            }
        }
        __builtin_amdgcn_s_setprio(0);
        if (it == qt) {   // only the diagonal tile needs masking
#pragma unroll
            for (int n = 0; n < 4; ++n) {
                int kvg = kv0 + n * 16 + lr;
#pragma unroll
                for (int r = 0; r < 4; ++r) {
                    float sv = s[n][r] * SCALE;
                    int qg = qrow0 + lg * 4 + r;
                    s[n][r] = (kvg > qg) ? -1e30f : sv;
                }
            }
        } else {
#pragma unroll
            for (int n = 0; n < 4; ++n)
#pragma unroll
                for (int r = 0; r < 4; ++r)
                    s[n][r] *= SCALE;
        }
        float tmax[4], rsum[4];
#pragma unroll
        for (int r = 0; r < 4; ++r)
            tmax[r] = fmaxf(fmaxf(s[0][r], s[1][r]), fmaxf(s[2][r], s[3][r]));
#pragma unroll
        for (int d = 1; d < 16; d <<= 1)
#pragma unroll
            for (int r = 0; r < 4; ++r)
                tmax[r] = fmaxf(tmax[r], __shfl_xor(tmax[r], d));
        // defer-max (T13): skip rescale when all rows grew by <= 8
        float need = fmaxf(fmaxf(tmax[0] - mrow[0], tmax[1] - mrow[1]),
                           fmaxf(tmax[2] - mrow[2], tmax[3] - mrow[3]));
        if (!__all(need <= 8.0f)) {
#pragma unroll
            for (int r = 0; r < 4; ++r) {
                float mnew = fmaxf(mrow[r], tmax[r]);
                float alpha = exp2f((mrow[r] - mnew) * L2E);
                mrow[r] = mnew;
                lrow[r] *= alpha;
#pragma unroll
                for (int v = 0; v < 8; ++v)
                    o[v][r] *= alpha;
            }
        }
        unsigned short pb[4][4];
#pragma unroll
        for (int r = 0; r < 4; ++r) rsum[r] = 0.f;
#pragma unroll
        for (int n = 0; n < 4; ++n)
#pragma unroll
            for (int r = 0; r < 4; ++r) {
                float p = exp2f((s[n][r] - mrow[r]) * L2E);
                rsum[r] += p;
                pb[n][r] = f2bf(p);
            }
#pragma unroll
        for (int d = 1; d < 16; d <<= 1)
#pragma unroll
            for (int r = 0; r < 4; ++r)
                rsum[r] += __shfl_xor(rsum[r], d);
#pragma unroll
        for (int r = 0; r < 4; ++r)
            lrow[r] += rsum[r];
        char* pbase = (char*)&Plds[wid][0];
#pragma unroll
        for (int n = 0; n < 4; ++n)
#pragma unroll
            for (int r = 0; r < 4; ++r) {
                int q = lg * 4 + r, kv = n * 16 + lr;
                int off = (q * 128 + kv * 2) ^ ((q & 7) << 4);
                *(unsigned short*)(pbase + off) = pb[n][r];
            }
        bf16x8 pa[2];
#pragma unroll
        for (int kk = 0; kk < 2; ++kk) {
            int aoff = (lr * 128 + kk * 64 + lg * 16) ^ ((lr & 7) << 4);
            pa[kk] = *(const bf16x8*)((const char*)pbase + aoff);
        }
        __builtin_amdgcn_s_setprio(1);
#pragma unroll
        for (int v = 0; v < 8; ++v) {
            int vcol = v * 16 + lr;
#pragma unroll
            for (int kk = 0; kk < 2; ++kk) {
                int boff = (vcol * 128 + kk * 64 + lg * 16) ^ ((vcol & 7) << 4);
                bf16x8 vb = *(const bf16x8*)((const char*)&Vlds[cur][0] + boff);
                o[v] = __builtin_amdgcn_mfma_f32_16x16x32_bf16(pa[kk], vb, o[v], 0, 0, 0);
            }
        }
        __builtin_amdgcn_s_setprio(0);
        __syncthreads();
    }
    const size_t pbo = (size_t)pidx * (64 * 128);
#pragma unroll
    for (int v = 0; v < 8; ++v)
#pragma unroll
        for (int r = 0; r < 4; ++r) {
            int row = wid * 16 + lg * 4 + r;
            part_o[pbo + (size_t)row * 128 + v * 16 + lr] = f2bf(o[v][r]);
        }
    if (lr == 0) {
#pragma unroll
        for (int r = 0; r < 4; ++r) {
            int row = wid * 16 + lg * 4 + r;
            part_ml[(size_t)pidx * 128 + row * 2]     = mrow[r];
            part_ml[(size_t)pidx * 128 + row * 2 + 1] = lrow[r];
        }
    }
}

// ---------------- kernel 4: combine partials (up to 8 chunks) ----------------
__global__ __launch_bounds__(256) void reduce_kernel(
    const unsigned short* __restrict__ part_o, const float* __restrict__ part_ml,
    float* __restrict__ out) {
    const int bid = blockIdx.x;
    const int rh = bid & 1, bq = bid >> 1;
    const int qt = bq & 31, b = bq >> 5;
    const int nch = (qt + CH) >> 2;
    int idx0 = 0;
    for (int q = 0; q < qt; ++q) idx0 += (q + CH) >> 2;
    const int pidx0 = b * CPB + idx0;
    const int t = threadIdx.x;
    const int row = rh * 32 + (t >> 3);
    const int col0 = (t & 7) * 16;

    float mc[8], lc[8];
#pragma unroll
    for (int cc = 0; cc < 8; ++cc) { mc[cc] = -1e30f; lc[cc] = 0.f; }
#pragma unroll
    for (int cc = 0; cc < 8; ++cc)
        if (cc < nch) {
            mc[cc] = part_ml[(size_t)(pidx0 + cc) * 128 + row * 2];
            lc[cc] = part_ml[(size_t)(pidx0 + cc) * 128 + row * 2 + 1];
        }
    float m = -1e30f;
#pragma unroll
    for (int cc = 0; cc < 8; ++cc) m = fmaxf(m, mc[cc]);
    float l = 0.f;
    float accv[16] = {};
#pragma unroll
    for (int cc = 0; cc < 8; ++cc)
        if (cc < nch) {
            float w = exp2f((mc[cc] - m) * L2E);
            l += w * lc[cc];
            const unsigned short* po = part_o + (size_t)(pidx0 + cc) * (64 * 128) + (size_t)row * 128 + col0;
            bf16x8 v0 = *(const bf16x8*)(po);
            bf16x8 v1 = *(const bf16x8*)(po + 8);
#pragma unroll
            for (int j = 0; j < 8; ++j) {
                accv[j]     += w * bf2f((unsigned short)v0[j]);
                accv[8 + j] += w * bf2f((unsigned short)v1[j]);
            }
        }
    const float inv = 1.f / l;
    float* op = out + ((size_t)b * Sn + qt * 64 + row) * ODn + Dn + col0;
#pragma unroll
    for (int j = 0; j < 4; ++j) {
        float4_t v = { accv[j*4] * inv, accv[j*4+1] * inv, accv[j*4+2] * inv, accv[j*4+3] * inv };
        *(float4_t*)(op + j * 4) = v;
    }
}

extern "C" void kernel_launch(void* const* d_in, const int* in_sizes, int n_in,
                              void* d_out, int out_size, void* d_ws, size_t ws_size,
                              hipStream_t stream) {
    const float* X  = (const float*)d_in[0];
    const float* Wq = (const float*)d_in[1];
    const float* bq = (const float*)d_in[2];
    const float* Wk = (const float*)d_in[3];
    const float* bk = (const float*)d_in[4];
    const float* Wv = (const float*)d_in[5];
    const float* bv = (const float*)d_in[6];
    float* out = (float*)d_out;

    unsigned short* Wt   = (unsigned short*)d_ws;                    // 3*128*1024 bf16
    unsigned short* qws  = Wt  + (size_t)3 * Kn * Dn;                // [4][2048][128] bf16
    unsigned short* kws  = qws + (size_t)Bn * Sn * Kn;
    unsigned short* vtws = kws + (size_t)Bn * Sn * Kn;               // [4][128][2048] bf16
    unsigned short* part_o = vtws + (size_t)Bn * Sn * Kn;            // [576][64][128] bf16
    float* part_ml = (float*)(part_o + (size_t)Bn * CPB * 64 * 128); // [576][64][2] f32

    wt_prep<<<dim3(32, 4, 3), 256, 0, stream>>>(Wq, Wk, Wv, Wt);
    proj_kernel<<<512, 256, 0, stream>>>(X, Wt, bq, bk, bv, out, qws, kws, vtws);
    attn_kernel<<<Bn * CPB, 256, 0, stream>>>(qws, kws, vtws, part_o, part_ml);
    reduce_kernel<<<256, 256, 0, stream>>>(part_o, part_ml, out);
}